// Round 4
// baseline (1673.320 us; speedup 1.0000x reference)
//
#include <hip/hip_runtime.h>
#include <math.h>

#define N_NODES 50000
#define N_EDGES 100000
#define FNODE 22
#define HDIM 64
#define BN_EPS 1e-5f

typedef __attribute__((ext_vector_type(8))) short bfrag;   // 8 bf16 = A/B operand
typedef __attribute__((ext_vector_type(4))) float facc;    // 4 f32  = C/D
typedef __attribute__((ext_vector_type(4))) unsigned int uint4v;
typedef __attribute__((ext_vector_type(2))) unsigned int uint2v;

__device__ __forceinline__ float readlane_f(float v, int lane) {
    return __uint_as_float(__builtin_amdgcn_readlane(__float_as_uint(v), (unsigned)lane));
}
__device__ __forceinline__ unsigned f2bf(float x) {  // RNE f32->bf16
    unsigned u = __float_as_uint(x);
    return (u + 0x7FFFu + ((u >> 16) & 1u)) >> 16;
}
__device__ __forceinline__ unsigned pk2bf(float lo, float hi) {
    return f2bf(lo) | (f2bf(hi) << 16);
}

// h1[n][o] = b1[o] + sum_i x[n][i] * root1[i][o]   (8 nodes per wave, lane = o)
__global__ void k_node1(const float* __restrict__ x, const float* __restrict__ root1,
                        const float* __restrict__ b1, float* __restrict__ h1) {
    __shared__ float rt[FNODE * HDIM];
    for (int idx = threadIdx.x; idx < FNODE * HDIM; idx += blockDim.x) rt[idx] = root1[idx];
    __syncthreads();
    int lane = threadIdx.x & 63;
    int wpb = blockDim.x >> 6;
    int wid = blockIdx.x * wpb + (threadIdx.x >> 6);
    int nw = gridDim.x * wpb;
    const int ngroups = N_NODES / 8;
    float bload = b1[lane];
    for (int g = wid; g < ngroups; g += nw) {
        int nbase = g * 8;
        float xr[8], acc[8];
#pragma unroll
        for (int e = 0; e < 8; ++e) {
            xr[e] = (lane < FNODE) ? x[(nbase + e) * FNODE + lane] : 0.f;
            acc[e] = bload;
        }
#pragma unroll
        for (int i = 0; i < FNODE; ++i) {
            float r = rt[i * HDIM + lane];
#pragma unroll
            for (int e = 0; e < 8; ++e)
                acc[e] = fmaf(readlane_f(xr[e], i), r, acc[e]);
        }
#pragma unroll
        for (int e = 0; e < 8; ++e) h1[(nbase + e) * HDIM + lane] = acc[e];
    }
}

// MFMA edge kernel: 32 edges per wave (2 groups of 16), c = i*64+o tiled by 16.
// A[m=c_local, k] = {We[0..3][c], be[c], 0,0,0}; B[k, n=e] = {ea[e,0..3], 1.0, 0...} (lanes>=16 zero)
// D: lane l -> e=l&15, o = o0 + (l>>4)*4 + reg   [m89 C/D layout]
// Output via per-wave LDS transpose -> one row-contiguous atomic instruction per edge
// (4 fully-covered 64B line-RMWs per edge; device-scope atomics are line-granular RMW).
#define TSTRIDE 68  // 32-row slab stride in floats: 68%32=4 -> 2-way bank alias (free)
template <int IN>
__launch_bounds__(256, 2)
__global__ void k_edge(const float* __restrict__ h, const float* __restrict__ ea,
                       const float* __restrict__ We, const float* __restrict__ be,
                       const int* __restrict__ eidx, float* __restrict__ out) {
    constexpr int INH = IN * HDIM;
    constexpr int HWORDS = (IN + 1) / 2;
    __shared__ unsigned Wlds[INH * 2];      // [c] -> 2 words = 4 bf16 (We rows 0..3)
    __shared__ unsigned short Belds[INH];   // be[c] bf16
    __shared__ float tbuf[4][32 * TSTRIDE]; // per-wave transpose slab
    for (int c = threadIdx.x; c < INH; c += blockDim.x) {
        Wlds[2 * c]     = pk2bf(We[c], We[INH + c]);
        Wlds[2 * c + 1] = pk2bf(We[2 * INH + c], We[3 * INH + c]);
        Belds[c] = (unsigned short)f2bf(be[c]);
    }
    __syncthreads();

    int lane = threadIdx.x & 63;
    int e16 = lane & 15;
    int orow = (lane >> 4) * 4;
    int wid = blockIdx.x * (blockDim.x >> 6) + (threadIdx.x >> 6);
    int ebase = wid * 32;
    if (ebase >= N_EDGES) return;
    float* tb = &tbuf[threadIdx.x >> 6][0];

    int src0 = eidx[ebase + e16];
    int src1 = eidx[ebase + 16 + e16];
    int dstl = (lane < 32) ? eidx[N_EDGES + ebase + lane] : 0;

    bool act = lane < 16;
    float4 ea0 = ((const float4*)ea)[ebase + e16];
    float4 ea1 = ((const float4*)ea)[ebase + 16 + e16];
    unsigned bone = act ? 0x3F80u : 0u;  // bf16(1.0) at k=4 multiplies be
    bfrag B0 = __builtin_bit_cast(bfrag, uint4v{act ? pk2bf(ea0.x, ea0.y) : 0u,
                                                act ? pk2bf(ea0.z, ea0.w) : 0u, bone, 0u});
    bfrag B1 = __builtin_bit_cast(bfrag, uint4v{act ? pk2bf(ea1.x, ea1.y) : 0u,
                                                act ? pk2bf(ea1.z, ea1.w) : 0u, bone, 0u});

    // lane-local h rows (bf16 packed) for this lane's edge in each group
    unsigned h0[HWORDS], h1w[HWORDS];
    if constexpr (IN == 64) {
        const float4* r0 = (const float4*)(h + (size_t)src0 * 64);
        const float4* r1 = (const float4*)(h + (size_t)src1 * 64);
#pragma unroll
        for (int w = 0; w < 16; ++w) {
            float4 v = r0[w];
            h0[2 * w] = pk2bf(v.x, v.y); h0[2 * w + 1] = pk2bf(v.z, v.w);
            float4 u = r1[w];
            h1w[2 * w] = pk2bf(u.x, u.y); h1w[2 * w + 1] = pk2bf(u.z, u.w);
        }
    } else {
        const float2* r0 = (const float2*)(h + (size_t)src0 * IN);
        const float2* r1 = (const float2*)(h + (size_t)src1 * IN);
#pragma unroll
        for (int w = 0; w < HWORDS; ++w) {
            float2 v = r0[w]; h0[w] = pk2bf(v.x, v.y);
            float2 u = r1[w]; h1w[w] = pk2bf(u.x, u.y);
        }
    }

    const facc zero4 = {0.f, 0.f, 0.f, 0.f};
    for (int o0 = 0; o0 < HDIM; o0 += 16) {
        facc msg0 = zero4, msg1 = zero4;
        const unsigned* wptr = &Wlds[2 * (o0 + e16)];
        const unsigned short* bptr = &Belds[o0 + e16];
#pragma unroll
        for (int i = 0; i < IN; ++i) {
            uint2v wv = *(const uint2v*)(wptr + (size_t)i * 128);      // ds_read_b64
            unsigned beu = (unsigned)bptr[(size_t)i * 64];             // ds_read_u16
            bfrag A = __builtin_bit_cast(bfrag, uint4v{wv.x, wv.y, beu, 0u});
            facc t0 = __builtin_amdgcn_mfma_f32_16x16x32_bf16(A, B0, zero4, 0, 0, 0);
            facc t1 = __builtin_amdgcn_mfma_f32_16x16x32_bf16(A, B1, zero4, 0, 0, 0);
            float hv0 = __uint_as_float((i & 1) ? (h0[i >> 1] & 0xFFFF0000u) : (h0[i >> 1] << 16));
            float hv1 = __uint_as_float((i & 1) ? (h1w[i >> 1] & 0xFFFF0000u) : (h1w[i >> 1] << 16));
#pragma unroll
            for (int j = 0; j < 4; ++j) {
                msg0[j] = fmaf(hv0, fmaxf(t0[j], 0.f), msg0[j]);
                msg1[j] = fmaf(hv1, fmaxf(t1[j], 0.f), msg1[j]);
            }
        }
        // stash fragments in per-wave LDS slab (ds_write_b128, 2-way bank alias)
        *(facc*)&tb[e16 * TSTRIDE + o0 + orow] = msg0;
        *(facc*)&tb[(16 + e16) * TSTRIDE + o0 + orow] = msg1;
    }

    // epilogue: one atomic instruction per edge, 64 contiguous dwords at uniform dst row
#pragma unroll
    for (int e = 0; e < 32; ++e) {
        int d = __builtin_amdgcn_readlane(dstl, e);
        float v = tb[e * TSTRIDE + lane];
        atomicAdd(&out[(size_t)d * HDIM + lane], v);
    }
}

// Per-channel sum & sumsq over N rows -> stats[0:64]=sum, stats[64:128]=sumsq (pre-zeroed)
__global__ void k_stats(const float* __restrict__ hbuf, float* stats) {
    int c = threadIdx.x & 63;
    int r = threadIdx.x >> 6;
    int rowsPer = blockDim.x >> 6;
    float s = 0.f, q = 0.f;
    for (int n = blockIdx.x * rowsPer + r; n < N_NODES; n += gridDim.x * rowsPer) {
        float v = hbuf[n * HDIM + c];
        s += v;
        q = fmaf(v, v, q);
    }
    __shared__ float ls[4][64], lq[4][64];
    ls[r][c] = s;
    lq[r][c] = q;
    __syncthreads();
    if (r == 0) {
        s = ls[0][c] + ls[1][c] + ls[2][c] + ls[3][c];
        q = lq[0][c] + lq[1][c] + lq[2][c] + lq[3][c];
        atomicAdd(&stats[c], s);
        atomicAdd(&stats[64 + c], q);
    }
}

__global__ void k_finalize(const float* stats_in, const float* __restrict__ g,
                           const float* __restrict__ beta, float* as_out) {
    int c = threadIdx.x;
    float mu = stats_in[c] * (1.f / N_NODES);
    float var = stats_in[64 + c] * (1.f / N_NODES) - mu * mu;
    var = fmaxf(var, 0.f);
    float a = g[c] * rsqrtf(var + BN_EPS);
    as_out[c] = a;
    as_out[64 + c] = beta[c] - mu * a;
}

// h1n = relu(BN1(h1)); h2 = b2 + h1n @ root2  (8 nodes per wave; h2 aliases h1 safely)
__global__ void k_apply1(const float* h1, const float* __restrict__ as1,
                         const float* __restrict__ root2, const float* __restrict__ b2,
                         float* __restrict__ h1n, float* h2) {
    __shared__ float rt[HDIM * HDIM];
    for (int idx = threadIdx.x; idx < HDIM * HDIM; idx += blockDim.x) rt[idx] = root2[idx];
    __syncthreads();
    int lane = threadIdx.x & 63;
    int wpb = blockDim.x >> 6;
    int wid = blockIdx.x * wpb + (threadIdx.x >> 6);
    int nw = gridDim.x * wpb;
    const int ngroups = N_NODES / 8;
    float a = as1[lane], s = as1[64 + lane];
    float bload = b2[lane];
    for (int g = wid; g < ngroups; g += nw) {
        int nbase = g * 8;
        float v[8], acc[8];
#pragma unroll
        for (int e = 0; e < 8; ++e) {
            v[e] = fmaxf(fmaf(h1[(nbase + e) * HDIM + lane], a, s), 0.f);
            h1n[(nbase + e) * HDIM + lane] = v[e];
            acc[e] = bload;
        }
#pragma unroll 4
        for (int i = 0; i < HDIM; ++i) {
            float r = rt[i * HDIM + lane];
#pragma unroll
            for (int e = 0; e < 8; ++e)
                acc[e] = fmaf(readlane_f(v[e], i), r, acc[e]);
        }
#pragma unroll
        for (int e = 0; e < 8; ++e) h2[(nbase + e) * HDIM + lane] = acc[e];
    }
}

// out[n] = sigmoid( sum_c relu(BN2(h2[n][c])) * Wfc[c] + bfc )
__global__ void k_final(const float* __restrict__ h2, const float* __restrict__ as2,
                        const float* __restrict__ Wfc, const float* __restrict__ bfc,
                        float* __restrict__ out) {
    int lane = threadIdx.x & 63;
    int n = blockIdx.x * (blockDim.x >> 6) + (threadIdx.x >> 6);
    if (n >= N_NODES) return;
    float a = as2[lane], s = as2[64 + lane];
    float v = fmaxf(fmaf(h2[n * HDIM + lane], a, s), 0.f) * Wfc[lane];
#pragma unroll
    for (int off = 32; off > 0; off >>= 1) v += __shfl_xor(v, off, 64);
    if (lane == 0) out[n] = 1.f / (1.f + expf(-(v + bfc[0])));
}

extern "C" void kernel_launch(void* const* d_in, const int* in_sizes, int n_in,
                              void* d_out, int out_size, void* d_ws, size_t ws_size,
                              hipStream_t stream) {
    const float* x     = (const float*)d_in[0];
    const float* ea    = (const float*)d_in[1];
    const float* We1   = (const float*)d_in[2];
    const float* be1   = (const float*)d_in[3];
    const float* root1 = (const float*)d_in[4];
    const float* b1    = (const float*)d_in[5];
    const float* g1    = (const float*)d_in[6];
    const float* beta1 = (const float*)d_in[7];
    const float* We2   = (const float*)d_in[8];
    const float* be2   = (const float*)d_in[9];
    const float* root2 = (const float*)d_in[10];
    const float* b2    = (const float*)d_in[11];
    const float* g2    = (const float*)d_in[12];
    const float* beta2 = (const float*)d_in[13];
    const float* Wfc   = (const float*)d_in[14];
    const float* bfc   = (const float*)d_in[15];
    const int*   eidx  = (const int*)d_in[16];
    float* out = (float*)d_out;

    char* ws = (char*)d_ws;
    const size_t nbuf = (size_t)N_NODES * HDIM * sizeof(float);
    float* h1    = (float*)ws;            // [N,64]
    float* h1n   = (float*)(ws + nbuf);   // [N,64]
    float* h2    = h1;                    // alias: h1 dead after k_apply1 reads it
    float* stats = (float*)(ws + 2 * nbuf);

    hipMemsetAsync(stats, 0, 512 * sizeof(float), stream);

    const int edgeBlocks = (N_EDGES / 32 + 3) / 4;  // 782: one 32-edge tile per wave
    const int nodeBlocks = (N_NODES + 3) / 4;

    k_node1<<<512, 256, 0, stream>>>(x, root1, b1, h1);
    k_edge<FNODE><<<edgeBlocks, 256, 0, stream>>>(x, ea, We1, be1, eidx, h1);
    k_stats<<<256, 256, 0, stream>>>(h1, stats);
    k_finalize<<<1, 64, 0, stream>>>(stats, g1, beta1, stats + 128);
    k_apply1<<<1024, 256, 0, stream>>>(h1, stats + 128, root2, b2, h1n, h2);
    k_edge<HDIM><<<edgeBlocks, 256, 0, stream>>>(h1n, ea, We2, be2, eidx, h2);
    k_stats<<<256, 256, 0, stream>>>(h2, stats + 256);
    k_finalize<<<1, 64, 0, stream>>>(stats + 256, g2, beta2, stats + 384);
    k_final<<<nodeBlocks, 256, 0, stream>>>(h2, stats + 384, Wfc, bfc, out);
}

// Round 5
// 209.781 us; speedup vs baseline: 7.9765x; 7.9765x over previous
//
#include <hip/hip_runtime.h>
#include <math.h>

#define N_NODES 50000
#define N_EDGES 100000
#define FNODE 22
#define HDIM 64
#define BN_EPS 1e-5f

typedef __attribute__((ext_vector_type(8))) short bfrag;   // 8 bf16 = A/B operand
typedef __attribute__((ext_vector_type(4))) float facc;    // 4 f32  = C/D
typedef __attribute__((ext_vector_type(4))) unsigned int uint4v;
typedef __attribute__((ext_vector_type(2))) unsigned int uint2v;

__device__ __forceinline__ float readlane_f(float v, int lane) {
    return __uint_as_float(__builtin_amdgcn_readlane(__float_as_uint(v), (unsigned)lane));
}
__device__ __forceinline__ unsigned f2bf(float x) {  // RNE f32->bf16
    unsigned u = __float_as_uint(x);
    return (u + 0x7FFFu + ((u >> 16) & 1u)) >> 16;
}
__device__ __forceinline__ unsigned pk2bf(float lo, float hi) {
    return f2bf(lo) | (f2bf(hi) << 16);
}

// h1[n][o] = b1[o] + sum_i x[n][i] * root1[i][o]   (8 nodes per wave, lane = o)
__global__ void k_node1(const float* __restrict__ x, const float* __restrict__ root1,
                        const float* __restrict__ b1, float* __restrict__ h1) {
    __shared__ float rt[FNODE * HDIM];
    for (int idx = threadIdx.x; idx < FNODE * HDIM; idx += blockDim.x) rt[idx] = root1[idx];
    __syncthreads();
    int lane = threadIdx.x & 63;
    int wpb = blockDim.x >> 6;
    int wid = blockIdx.x * wpb + (threadIdx.x >> 6);
    int nw = gridDim.x * wpb;
    const int ngroups = N_NODES / 8;
    float bload = b1[lane];
    for (int g = wid; g < ngroups; g += nw) {
        int nbase = g * 8;
        float xr[8], acc[8];
#pragma unroll
        for (int e = 0; e < 8; ++e) {
            xr[e] = (lane < FNODE) ? x[(nbase + e) * FNODE + lane] : 0.f;
            acc[e] = bload;
        }
#pragma unroll
        for (int i = 0; i < FNODE; ++i) {
            float r = rt[i * HDIM + lane];
#pragma unroll
            for (int e = 0; e < 8; ++e)
                acc[e] = fmaf(readlane_f(xr[e], i), r, acc[e]);
        }
#pragma unroll
        for (int e = 0; e < 8; ++e) h1[(nbase + e) * HDIM + lane] = acc[e];
    }
}

// MFMA edge kernel, SWAPPED operand roles: A = edge attrs (M=16 edges/group, 2 groups),
// B = weights (N=16 output channels per o0 tile). K slots 0..3 = We rows, slot 4 = bias
// (A carries 1.0, B carries be). D layout [m89]: col(lane&15)=o, row((lane>>4)*4+reg)=edge
// -> epilogue atomic instr covers 16 contiguous dwords x 4 edges = 4 fully-covered 64B lines.
// h read per-i from a small per-wave LDS slab (broadcast reads), msg = 32 VGPRs. No spill.
template <int IN, int HSTRIDE>
__launch_bounds__(256, 2)
__global__ void k_edge(const float* __restrict__ h, const float* __restrict__ ea,
                       const float* __restrict__ We, const float* __restrict__ be,
                       const int* __restrict__ eidx, float* __restrict__ out) {
    constexpr int INH = IN * HDIM;
    __shared__ unsigned Wlds[INH * 2];      // [c] -> 2 words = 4 bf16 (We rows 0..3)
    __shared__ unsigned short Belds[INH];   // be[c] bf16
    __shared__ float hsl[4][32 * HSTRIDE];  // per-wave h rows (f32)
    for (int c = threadIdx.x; c < INH; c += blockDim.x) {
        Wlds[2 * c]     = pk2bf(We[c], We[INH + c]);
        Wlds[2 * c + 1] = pk2bf(We[2 * INH + c], We[3 * INH + c]);
        Belds[c] = (unsigned short)f2bf(be[c]);
    }
    __syncthreads();

    int lane = threadIdx.x & 63;
    int e16 = lane & 15;                 // D column = o offset
    int orow4 = (lane >> 4) * 4;         // D row base = edge-within-group base
    int wid = blockIdx.x * (blockDim.x >> 6) + (threadIdx.x >> 6);
    int ebase = wid * 32;
    if (ebase >= N_EDGES) return;
    float* hs = &hsl[threadIdx.x >> 6][0];

    // A operands: lanes<16 carry k=0..4 = {ea[e], 1.0}; all other k-slots zero
    bool act = lane < 16;
    float4 ea0 = ((const float4*)ea)[ebase + e16];
    float4 ea1 = ((const float4*)ea)[ebase + 16 + e16];
    unsigned aone = act ? 0x3F80u : 0u;
    bfrag A0 = __builtin_bit_cast(bfrag, uint4v{act ? pk2bf(ea0.x, ea0.y) : 0u,
                                                act ? pk2bf(ea0.z, ea0.w) : 0u, aone, 0u});
    bfrag A1 = __builtin_bit_cast(bfrag, uint4v{act ? pk2bf(ea1.x, ea1.y) : 0u,
                                                act ? pk2bf(ea1.z, ea1.w) : 0u, aone, 0u});

    // stage this wave's 32 h rows into its LDS slab (coalesced-ish; wave-local, no barrier)
    if constexpr (IN == 64) {
#pragma unroll
        for (int p = 0; p < 8; ++p) {
            int idx = p * 64 + lane;
            int r = idx >> 4, c4 = idx & 15;
            int srcr = eidx[ebase + r];
            float4 v = *(const float4*)(h + (size_t)srcr * 64 + c4 * 4);
            *(float4*)&hs[r * HSTRIDE + c4 * 4] = v;
        }
    } else {
#pragma unroll
        for (int p = 0; p < (32 * IN) / 64; ++p) {   // 704 = 11*64 exact for IN=22
            int idx = p * 64 + lane;
            int r = idx / IN, c = idx - r * IN;
            int srcr = eidx[ebase + r];
            hs[r * HSTRIDE + c] = h[(size_t)srcr * IN + c];
        }
    }

    // dst row indices for this lane's 8 (group, reg) slots
    int dA[4], dB[4];
#pragma unroll
    for (int j = 0; j < 4; ++j) {
        dA[j] = eidx[N_EDGES + ebase + orow4 + j];
        dB[j] = eidx[N_EDGES + ebase + 16 + orow4 + j];
    }

    const facc zero4 = {0.f, 0.f, 0.f, 0.f};
    facc m0[4], m1[4];
#pragma unroll
    for (int t = 0; t < 4; ++t) { m0[t] = zero4; m1[t] = zero4; }

    unsigned msk = act ? 0xFFFFFFFFu : 0u;
    const unsigned* wbase = &Wlds[2 * e16];
    const unsigned short* bbase = &Belds[e16];

#pragma unroll 2
    for (int i = 0; i < IN; ++i) {
        float hv0[4], hv1[4];
#pragma unroll
        for (int j = 0; j < 4; ++j) {                       // broadcast reads, 4 addrs/instr
            hv0[j] = hs[(orow4 + j) * HSTRIDE + i];
            hv1[j] = hs[(16 + orow4 + j) * HSTRIDE + i];
        }
#pragma unroll
        for (int t = 0; t < 4; ++t) {
            uint2v wv = *(const uint2v*)(wbase + i * 128 + t * 32);   // ds_read_b64
            unsigned beu = (unsigned)bbase[i * 64 + t * 16];          // ds_read_u16
            bfrag B = __builtin_bit_cast(bfrag, uint4v{wv.x & msk, wv.y & msk, beu & msk, 0u});
            facc t0 = __builtin_amdgcn_mfma_f32_16x16x32_bf16(A0, B, zero4, 0, 0, 0);
            facc t1 = __builtin_amdgcn_mfma_f32_16x16x32_bf16(A1, B, zero4, 0, 0, 0);
#pragma unroll
            for (int j = 0; j < 4; ++j) {
                m0[t][j] = fmaf(hv0[j], fmaxf(t0[j], 0.f), m0[t][j]);
                m1[t][j] = fmaf(hv1[j], fmaxf(t1[j], 0.f), m1[t][j]);
            }
        }
    }

    // epilogue: each atomic instr = 4 edges x 16 contiguous dwords (4 fully-covered lines)
#pragma unroll
    for (int t = 0; t < 4; ++t) {
#pragma unroll
        for (int j = 0; j < 4; ++j) {
            atomicAdd(&out[(size_t)dA[j] * HDIM + t * 16 + e16], m0[t][j]);
            atomicAdd(&out[(size_t)dB[j] * HDIM + t * 16 + e16], m1[t][j]);
        }
    }
}

// Per-channel sum & sumsq over N rows -> stats[0:64]=sum, stats[64:128]=sumsq (pre-zeroed)
__global__ void k_stats(const float* __restrict__ hbuf, float* stats) {
    int c = threadIdx.x & 63;
    int r = threadIdx.x >> 6;
    int rowsPer = blockDim.x >> 6;
    float s = 0.f, q = 0.f;
    for (int n = blockIdx.x * rowsPer + r; n < N_NODES; n += gridDim.x * rowsPer) {
        float v = hbuf[n * HDIM + c];
        s += v;
        q = fmaf(v, v, q);
    }
    __shared__ float ls[4][64], lq[4][64];
    ls[r][c] = s;
    lq[r][c] = q;
    __syncthreads();
    if (r == 0) {
        s = ls[0][c] + ls[1][c] + ls[2][c] + ls[3][c];
        q = lq[0][c] + lq[1][c] + lq[2][c] + lq[3][c];
        atomicAdd(&stats[c], s);
        atomicAdd(&stats[64 + c], q);
    }
}

__global__ void k_finalize(const float* stats_in, const float* __restrict__ g,
                           const float* __restrict__ beta, float* as_out) {
    int c = threadIdx.x;
    float mu = stats_in[c] * (1.f / N_NODES);
    float var = stats_in[64 + c] * (1.f / N_NODES) - mu * mu;
    var = fmaxf(var, 0.f);
    float a = g[c] * rsqrtf(var + BN_EPS);
    as_out[c] = a;
    as_out[64 + c] = beta[c] - mu * a;
}

// h1n = relu(BN1(h1)); h2 = b2 + h1n @ root2  (8 nodes per wave; h2 aliases h1 safely)
__global__ void k_apply1(const float* h1, const float* __restrict__ as1,
                         const float* __restrict__ root2, const float* __restrict__ b2,
                         float* __restrict__ h1n, float* h2) {
    __shared__ float rt[HDIM * HDIM];
    for (int idx = threadIdx.x; idx < HDIM * HDIM; idx += blockDim.x) rt[idx] = root2[idx];
    __syncthreads();
    int lane = threadIdx.x & 63;
    int wpb = blockDim.x >> 6;
    int wid = blockIdx.x * wpb + (threadIdx.x >> 6);
    int nw = gridDim.x * wpb;
    const int ngroups = N_NODES / 8;
    float a = as1[lane], s = as1[64 + lane];
    float bload = b2[lane];
    for (int g = wid; g < ngroups; g += nw) {
        int nbase = g * 8;
        float v[8], acc[8];
#pragma unroll
        for (int e = 0; e < 8; ++e) {
            v[e] = fmaxf(fmaf(h1[(nbase + e) * HDIM + lane], a, s), 0.f);
            h1n[(nbase + e) * HDIM + lane] = v[e];
            acc[e] = bload;
        }
#pragma unroll 4
        for (int i = 0; i < HDIM; ++i) {
            float r = rt[i * HDIM + lane];
#pragma unroll
            for (int e = 0; e < 8; ++e)
                acc[e] = fmaf(readlane_f(v[e], i), r, acc[e]);
        }
#pragma unroll
        for (int e = 0; e < 8; ++e) h2[(nbase + e) * HDIM + lane] = acc[e];
    }
}

// out[n] = sigmoid( sum_c relu(BN2(h2[n][c])) * Wfc[c] + bfc )
__global__ void k_final(const float* __restrict__ h2, const float* __restrict__ as2,
                        const float* __restrict__ Wfc, const float* __restrict__ bfc,
                        float* __restrict__ out) {
    int lane = threadIdx.x & 63;
    int n = blockIdx.x * (blockDim.x >> 6) + (threadIdx.x >> 6);
    if (n >= N_NODES) return;
    float a = as2[lane], s = as2[64 + lane];
    float v = fmaxf(fmaf(h2[n * HDIM + lane], a, s), 0.f) * Wfc[lane];
#pragma unroll
    for (int off = 32; off > 0; off >>= 1) v += __shfl_xor(v, off, 64);
    if (lane == 0) out[n] = 1.f / (1.f + expf(-(v + bfc[0])));
}

extern "C" void kernel_launch(void* const* d_in, const int* in_sizes, int n_in,
                              void* d_out, int out_size, void* d_ws, size_t ws_size,
                              hipStream_t stream) {
    const float* x     = (const float*)d_in[0];
    const float* ea    = (const float*)d_in[1];
    const float* We1   = (const float*)d_in[2];
    const float* be1   = (const float*)d_in[3];
    const float* root1 = (const float*)d_in[4];
    const float* b1    = (const float*)d_in[5];
    const float* g1    = (const float*)d_in[6];
    const float* beta1 = (const float*)d_in[7];
    const float* We2   = (const float*)d_in[8];
    const float* be2   = (const float*)d_in[9];
    const float* root2 = (const float*)d_in[10];
    const float* b2    = (const float*)d_in[11];
    const float* g2    = (const float*)d_in[12];
    const float* beta2 = (const float*)d_in[13];
    const float* Wfc   = (const float*)d_in[14];
    const float* bfc   = (const float*)d_in[15];
    const int*   eidx  = (const int*)d_in[16];
    float* out = (float*)d_out;

    char* ws = (char*)d_ws;
    const size_t nbuf = (size_t)N_NODES * HDIM * sizeof(float);
    float* h1    = (float*)ws;            // [N,64]
    float* h1n   = (float*)(ws + nbuf);   // [N,64]
    float* h2    = h1;                    // alias: h1 dead after k_apply1 reads it
    float* stats = (float*)(ws + 2 * nbuf);

    hipMemsetAsync(stats, 0, 512 * sizeof(float), stream);

    const int edgeBlocks = (N_EDGES / 32 + 3) / 4;  // 782: one 32-edge tile per wave
    const int nodeBlocks = (N_NODES + 3) / 4;

    k_node1<<<512, 256, 0, stream>>>(x, root1, b1, h1);
    k_edge<FNODE, 23><<<edgeBlocks, 256, 0, stream>>>(x, ea, We1, be1, eidx, h1);
    k_stats<<<256, 256, 0, stream>>>(h1, stats);
    k_finalize<<<1, 64, 0, stream>>>(stats, g1, beta1, stats + 128);
    k_apply1<<<1024, 256, 0, stream>>>(h1, stats + 128, root2, b2, h1n, h2);
    k_edge<HDIM, 68><<<edgeBlocks, 256, 0, stream>>>(h1n, ea, We2, be2, eidx, h2);
    k_stats<<<256, 256, 0, stream>>>(h2, stats + 256);
    k_finalize<<<1, 64, 0, stream>>>(stats + 256, g2, beta2, stats + 384);
    k_final<<<nodeBlocks, 256, 0, stream>>>(h2, stats + 384, Wfc, bfc, out);
}